// Round 10
// baseline (3571.843 us; speedup 1.0000x reference)
//
#include <hip/hip_runtime.h>
#include <hip/hip_fp16.h>

// ---------------------------------------------------------------------------
// DeterministicLSTMSensorBasedForwardDynamics on MI355X (gfx950) — round 10
//
// r8/r9 falsified barrier-drain and L2-convoy theories; the 264-us plateau is
// latency-bound weight STREAMING (384 KB/CU/step, 8-deep ring, 2 waves/SIMD)
// with every register/LDS lever pinned. Round 10 deletes the stream:
//   * WG PAIR-SPLIT: pair (p, p+128) shares batch rows [32p,32p+32); WG half
//     H computes all 4 gates for h-cols [H*128,H*128+128). Per wave: 44
//     weight blocks = 32 in AGPR-backed registers (kt0..7) + 12 in LDS
//     (kt8..10) -> FULLY RESIDENT, steady-state weight stream = 0 B.
//   * Per-step h-exchange (8 KB) between partners via LLC: plain stores ->
//     per-wave RELEASE atomicAdd(flag) (agent scope: drains + writes back) ->
//     bounded spin ACQUIRE on partner flag -> agent-scope atomic loads ->
//     ds_write into next A panel. Flags t-indexed, zeroed each launch by the
//     repack kernel (ws re-poison safe). Buffers double-buffered (t&1); the
//     anti-dependency is ordered by the flag chain (write(t+2) happens-after
//     receive(t+1) happens-after partner-read(t)).
//   * Grid 256 WGs x 144 KB LDS -> 1 WG/CU -> all 256 co-resident
//     (persistent-kernel invariant). Spin is bounded -> no hang possible.
//   * MLP head: pair splits by ROWS (16 each) -> no further exchange.
// ws: weights 1.41 MB | exchange 4 MB | flags 64 KB  (~5.7 MB total).
// ---------------------------------------------------------------------------

typedef _Float16 h8 __attribute__((ext_vector_type(8)));
typedef _Float16 hv4 __attribute__((ext_vector_type(4)));
typedef float f4 __attribute__((ext_vector_type(4)));

#define NB    4096
#define TSEQ  50
#define DOBS  64
#define DACT  16
#define HD    256
#define DOUT  64
#define NL    5

#define NKT   11        // K-tiles of 32 covering 352 = 80 (x) + 256 (h) + 16 pad
#define AROW  360       // LDS A-row stride in halves
#define MTILE 32        // rows per WG PAIR (each WG does all 32 rows, half cols)
#define NWG   256       // 128 pairs x 2 halves; 1 WG/CU -> all co-resident
#define NTHR  512       // 8 waves

// ws layout: weights (halves), then exchange buffers, then flags (bytes)
#define WS_MLP     (704 * 512)
#define WS_WOUT    (WS_MLP + 640 * 512)
#define WS_W_BYTES (1376 * 512 * 2)                 // 1,409,024
#define EX_OFF     WS_W_BYTES                       // 128 pairs x 2 half x 2 slot x 8 KB
#define EX_BYTES   (128 * 2 * 2 * 8192)             // 4,194,304
#define FLAG_OFF   (EX_OFF + EX_BYTES)              // 16384 uints (64 per pair-half)
#define NFLAGS     (128 * 2 * 64)

// LDS layout (halves): As0 | As1 | Wcache(8 waves x 12 blocks)
#define LDS_AS     (MTILE * AROW)                   // 11520
#define LDS_WCOFF  (2 * LDS_AS)                     // 23040
#define WCB        12                               // LDS-resident blocks/wave (kt8..10)
#define LDS_HALVES (LDS_WCOFF + 8 * WCB * 512)      // 72192
#define LDS_BYTES  (LDS_HALVES * 2)                 // 144384 (<= 160 KiB)
static_assert(LDS_BYTES <= 160 * 1024, "LDS overflow");

// LDS-only barrier (r8: >= __syncthreads, lets any in-flight vmem keep flying)
__device__ __forceinline__ void lds_barrier() {
  asm volatile("s_waitcnt lgkmcnt(0)\n\ts_barrier" ::: "memory");
}

// sigmoid via native v_exp_f32 + v_rcp_f32 (1-ulp; fp16 weights dominate err).
__device__ __forceinline__ float sigf(float x) {
  const float e = __builtin_amdgcn_exp2f(x * -1.44269504088896f);
  return __builtin_amdgcn_rcpf(1.f + e);
}

// --------------------------- weight repack + flag init ---------------------
__global__ void __launch_bounds__(256) repack_kernel(
    const float* __restrict__ Wi, const float* __restrict__ Wh,
    const float* __restrict__ mlpW, const float* __restrict__ Wout,
    _Float16* __restrict__ wsW, unsigned* __restrict__ flags)
{
  const int gt  = blockIdx.x * 256 + threadIdx.x;
  if (gt < NFLAGS) flags[gt] = 0u;     // re-poison-safe flag init, every launch
  const int gb  = gt >> 6;
  const int l   = gt & 63;
  const int l15 = l & 15;
  const int kb  = (l >> 4) * 8;
  h8 v;
  if (gb < 704) {                       // LSTM: Wcat[k][n], k<80 -> Wi, k<336 -> Wh, else 0
    const int nt = gb / NKT, kt = gb - nt * NKT;
    const int n  = nt * 16 + l15;
#pragma unroll
    for (int j = 0; j < 8; ++j) {
      const int k = kt * 32 + kb + j;
      float s = 0.f;
      if (k < 80)       s = Wi[k * 1024 + n];
      else if (k < 336) s = Wh[(k - 80) * 1024 + n];
      v[j] = (_Float16)s;
    }
  } else if (gb < 1344) {               // MLP layer weights [5][256][256]
    const int b2 = gb - 704;
    const int L  = b2 >> 7, rr = b2 & 127;
    const int nt = rr >> 3, kt = rr & 7;
    const int n  = nt * 16 + l15;
#pragma unroll
    for (int j = 0; j < 8; ++j) {
      const int k = kt * 32 + kb + j;
      v[j] = (_Float16)mlpW[(size_t)L * 65536 + k * 256 + n];
    }
  } else {                              // Wout [256][64]
    const int b3 = gb - 1344;
    const int nt = b3 >> 3, kt = b3 & 7;
    const int n  = nt * 16 + l15;
#pragma unroll
    for (int j = 0; j < 8; ++j) {
      const int k = kt * 32 + kb + j;
      v[j] = (_Float16)Wout[k * 64 + n];
    }
  }
  *(h8*)&wsW[(size_t)gb * 512 + l * 8] = v;
}

// ------------------------------ main kernel --------------------------------
__global__ void __launch_bounds__(NTHR, 2) lstm_kernel(
    const float* __restrict__ traj, const float* __restrict__ acts,
    const float* __restrict__ bh,   const float* __restrict__ mlpb,
    const float* __restrict__ bout, const _Float16* __restrict__ wsW,
    _Float16* __restrict__ exbuf,   unsigned* __restrict__ flags,
    float* __restrict__ out)
{
  extern __shared__ __align__(16) _Float16 lds[];
  _Float16* As0 = lds;
  _Float16* As1 = lds + LDS_AS;
  _Float16* Wc  = lds + LDS_WCOFF;

  const int tid = threadIdx.x;
  const int w   = tid >> 6;
  const int l   = tid & 63;
  const int l15 = l & 15;
  const int lq  = l >> 4;

  const int pair = (int)(blockIdx.x & 127);
  const int H    = (int)(blockIdx.x >> 7);     // column half: 0 or 1
  const int rbase = pair * MTILE;              // 32 batch rows shared by the pair
  const int ntw  = H * 8 + w;                  // this wave's h-col tile (of 16)
  const int myslot = (pair * 2 + H) * 64;      // flag base (t-indexed)
  const int pslot  = (pair * 2 + (1 - H)) * 64;

  // Zero both A panels (h starts 0; pad cols 336..359 stay 0 forever).
  for (int i = tid; i < 2 * LDS_AS; i += NTHR) lds[i] = (_Float16)0.f;

  // LDS-resident: 12 blocks/wave = (kt8..10, g0..3) for this wave's column.
#pragma unroll
  for (int j = 0; j < WCB; ++j) {
    const int g = j & 3, kt = 8 + (j >> 2);
    const h8 v = *(const h8*)&wsW[(size_t)((g * 16 + ntw) * NKT + kt) * 512 + l * 8];
    *(h8*)&Wc[(w * WCB + j) * 512 + l * 8] = v;
  }

  // Register-resident: 32 blocks/wave = (kt0..7, g0..3) — AGPR-backed.
  h8 rw[32];
#pragma unroll
  for (int kt = 0; kt < 8; ++kt)
#pragma unroll
    for (int g = 0; g < 4; ++g)
      rw[kt * 4 + g] = *(const h8*)&wsW[(size_t)((g * 16 + ntw) * NKT + kt) * 512 + l * 8];

  // Persistent cell state [mt][r] + gate biases
  float c[2][4];
#pragma unroll
  for (int mt = 0; mt < 2; ++mt)
#pragma unroll
    for (int r = 0; r < 4; ++r) c[mt][r] = 0.f;

  float bias[4];
#pragma unroll
  for (int g = 0; g < 4; ++g) bias[g] = bh[g * 256 + ntw * 16 + l15];

  __syncthreads();

  // Stage x_0 into As0 cols 0..79 (each thread owns one (row, quarter)).
  {
    const int r = tid >> 4, q = tid & 15;
    const float4 v = *(const float4*)&traj[(size_t)(rbase + r) * (TSEQ * DOBS) + q * 4];
    hv4 hx = { (_Float16)v.x, (_Float16)v.y, (_Float16)v.z, (_Float16)v.w };
    *(hv4*)&As0[r * AROW + q * 4] = hx;
    As0[r * AROW + 64 + q] = (_Float16)acts[(size_t)(rbase + r) * (TSEQ * DACT) + q];
  }
  __syncthreads();

  unsigned long long wbits = (unsigned long long)(const void*)wsW;

  auto step = [&](int t, const _Float16* buf, _Float16* nbuf) {
    // Clobber: rw[] can't be legally rematerialized from wsW -> stays resident.
    asm volatile("" : "+s"(wbits) : : "memory");

    // x(t+1): load to registers now, store to LDS at end of step.
    float4 xv; float xa;
    const bool havex = (t + 1 < TSEQ);
    const int xr = tid >> 4, xq = tid & 15;
    if (havex) {
      xv = *(const float4*)&traj[(size_t)(rbase + xr) * (TSEQ * DOBS) + (t + 1) * DOBS + xq * 4];
      xa = acts[(size_t)(rbase + xr) * (TSEQ * DACT) + (t + 1) * DACT + xq];
    }

    // ---------------- K-loop: fully on-chip (32 reg + 12 LDS blocks) -------
    f4 acc[4][2];   // [gate][mtile]
#pragma unroll
    for (int g = 0; g < 4; ++g) { acc[g][0] = f4{0.f,0.f,0.f,0.f}; acc[g][1] = f4{0.f,0.f,0.f,0.f}; }

#pragma unroll
    for (int kt = 0; kt < NKT; ++kt) {
      const h8 a0 = *(const h8*)&buf[l15 * AROW + kt * 32 + lq * 8];
      const h8 a1 = *(const h8*)&buf[(16 + l15) * AROW + kt * 32 + lq * 8];
#pragma unroll
      for (int g = 0; g < 4; ++g) {
        const h8 bf = (kt < 8) ? rw[kt * 4 + g]
                   : *(const h8*)&Wc[(w * WCB + (kt - 8) * 4 + g) * 512 + l * 8];
        acc[g][0] = __builtin_amdgcn_mfma_f32_16x16x32_f16(a0, bf, acc[g][0], 0, 0, 0);
        acc[g][1] = __builtin_amdgcn_mfma_f32_16x16x32_f16(a1, bf, acc[g][1], 0, 0, 0);
      }
    }

    // ---------------- cell update + publish own half -----------------------
    _Float16* exown = exbuf + (size_t)(((pair * 2 + H) * 2 + (t & 1))) * 4096;
    const int colh = 80 + H * 128 + w * 16 + l15;   // col in A panel
    const int colx = w * 16 + l15;                  // col in exchange buffer
#pragma unroll
    for (int mt = 0; mt < 2; ++mt)
#pragma unroll
      for (int r = 0; r < 4; ++r) {
        const float zi = acc[0][mt][r] + bias[0];
        const float zf = acc[1][mt][r] + bias[1];
        const float zg = acc[2][mt][r] + bias[2];
        const float zo = acc[3][mt][r] + bias[3];
        const float ig = sigf(zi), fg = sigf(zf), og = sigf(zo);
        const float gg = zg * sigf(zg);
        const float cn = fg * c[mt][r] + ig * gg;
        c[mt][r] = cn;
        const _Float16 hh = (_Float16)(og * cn * sigf(cn));
        const int row = mt * 16 + lq * 4 + r;
        nbuf[row * AROW + colh] = hh;
        exown[row * 128 + colx] = hh;
      }

    // Deferred x(t+1) store into nbuf cols 0..79.
    if (havex) {
      hv4 hx = { (_Float16)xv.x, (_Float16)xv.y, (_Float16)xv.z, (_Float16)xv.w };
      *(hv4*)&nbuf[xr * AROW + xq * 4] = hx;
      nbuf[xr * AROW + 64 + xq] = (_Float16)xa;
    }

    // RELEASE: per-wave flag add (drains this wave's stores, writes back L2).
    if (l == 0)
      __hip_atomic_fetch_add(&flags[myslot + t], 1u,
                             __ATOMIC_RELEASE, __HIP_MEMORY_SCOPE_AGENT);

    // Bounded spin for partner's 8 waves (ACQUIRE on success path).
    {
      int polls = 0;
      for (;;) {
        unsigned v = 0;
        if (l == 0)
          v = __hip_atomic_load(&flags[pslot + t],
                                __ATOMIC_ACQUIRE, __HIP_MEMORY_SCOPE_AGENT);
        v = (unsigned)__shfl((int)v, 0, 64);
        if (v == 8u || ++polls >= (1 << 24)) break;   // bound -> no hang
        __builtin_amdgcn_s_sleep(1);
      }
    }

    // Stage partner half (agent-scope loads bypass stale caches) -> A panel.
    {
      const unsigned* pex = (const unsigned*)
          (exbuf + (size_t)(((pair * 2 + (1 - H)) * 2 + (t & 1))) * 4096);
      const unsigned* ps = pex + xr * 64 + xq * 4;   // 16 B per thread
      union { unsigned u[4]; h8 v; } d;
#pragma unroll
      for (int j = 0; j < 4; ++j)
        d.u[j] = __hip_atomic_load(&ps[j], __ATOMIC_RELAXED, __HIP_MEMORY_SCOPE_AGENT);
      *(h8*)&nbuf[xr * AROW + 80 + (1 - H) * 128 + xq * 8] = d.v;
    }
  };

#pragma unroll 1
  for (int t = 0; t < TSEQ; t += 2) {
    step(t, As0, As1);
    lds_barrier();
    step(t + 1, As1, As0);
    lds_barrier();
  }

  // ---------------- MLP head: pair splits by ROWS (16 each) ----------------
  // Final full h(50) in As0 cols 80..335. This WG takes rows [H*16, H*16+16).
  const int ro = H * 16;
  for (int i = tid; i < 16 * HD; i += NTHR) {
    const int r = i >> 8, cc = i & 255;
    As1[r * AROW + cc] = As0[(ro + r) * AROW + 80 + cc];
  }
  __syncthreads();

#pragma unroll 1
  for (int L = 0; L < NL; ++L) {
    const _Float16* in = (L & 1) ? As0 : As1;
    _Float16*       ob = (L & 1) ? As1 : As0;
    const _Float16* wl = wsW + WS_MLP + (size_t)L * (128 * 512);
    float bcol[2];
    bcol[0] = mlpb[L * HD + w * 32 + l15];
    bcol[1] = mlpb[L * HD + w * 32 + 16 + l15];

    f4 acc[2];
    acc[0] = f4{0.f, 0.f, 0.f, 0.f};
    acc[1] = f4{0.f, 0.f, 0.f, 0.f};
#pragma unroll
    for (int kt = 0; kt < 8; ++kt) {
      const h8 a0 = *(const h8*)&in[l15 * AROW + kt * 32 + lq * 8];
#pragma unroll
      for (int cb = 0; cb < 2; ++cb) {
        const h8 bf = *(const h8*)&wl[(size_t)((w * 2 + cb) * 8 + kt) * 512 + l * 8];
        acc[cb] = __builtin_amdgcn_mfma_f32_16x16x32_f16(a0, bf, acc[cb], 0, 0, 0);
      }
    }
#pragma unroll
    for (int cb = 0; cb < 2; ++cb)
#pragma unroll
      for (int r = 0; r < 4; ++r) {
        const float z = acc[cb][r] + bcol[cb];
        ob[(lq * 4 + r) * AROW + w * 32 + cb * 16 + l15] = (_Float16)(z * sigf(z));
      }
    __syncthreads();
  }

  // Output layer: final activations in As0 (NL=5 odd). N=64 -> waves 0..3.
  if (w < 4) {
    const _Float16* wo = wsW + WS_WOUT;
    const float bo = bout[w * 16 + l15];
    f4 acc0 = f4{0.f, 0.f, 0.f, 0.f};
#pragma unroll
    for (int kt = 0; kt < 8; ++kt) {
      const h8 a0 = *(const h8*)&As0[l15 * AROW + kt * 32 + lq * 8];
      const h8 bf = *(const h8*)&wo[(size_t)(w * 8 + kt) * 512 + l * 8];
      acc0 = __builtin_amdgcn_mfma_f32_16x16x32_f16(a0, bf, acc0, 0, 0, 0);
    }
#pragma unroll
    for (int r = 0; r < 4; ++r)
      out[(size_t)(rbase + ro + lq * 4 + r) * DOUT + w * 16 + l15] = acc0[r] + bo;
  }
}

// ------------------------------- launcher ----------------------------------
extern "C" void kernel_launch(void* const* d_in, const int* in_sizes, int n_in,
                              void* d_out, int out_size, void* d_ws, size_t ws_size,
                              hipStream_t stream)
{
  const float* traj = (const float*)d_in[0];
  const float* acts = (const float*)d_in[1];
  const float* Wi   = (const float*)d_in[2];
  const float* Wh   = (const float*)d_in[3];
  const float* bh   = (const float*)d_in[4];
  const float* mlpW = (const float*)d_in[5];
  const float* mlpb = (const float*)d_in[6];
  const float* Wout = (const float*)d_in[7];
  const float* bout = (const float*)d_in[8];

  char* wsb = (char*)d_ws;                       // needs ~5.7 MB of workspace
  _Float16* wsW   = (_Float16*)wsb;
  _Float16* exbuf = (_Float16*)(wsb + EX_OFF);
  unsigned* flags = (unsigned*)(wsb + FLAG_OFF);

  (void)hipFuncSetAttribute((const void*)lstm_kernel,
                            hipFuncAttributeMaxDynamicSharedMemorySize, LDS_BYTES);

  repack_kernel<<<344, 256, 0, stream>>>(Wi, Wh, mlpW, Wout, wsW, flags);
  lstm_kernel<<<NWG, NTHR, LDS_BYTES, stream>>>(traj, acts, bh, mlpb, bout,
                                                wsW, exbuf, flags, (float*)d_out);
}